// Round 2
// baseline (189.030 us; speedup 1.0000x reference)
//
#include <hip/hip_runtime.h>

#define NP      4096
#define WINDOW  327
#define HALF    163
#define RL      20
#define NA      262144
#define GN_EPS  1e-6f

// fast tanh: tanh(x) = 1 - 2/(e^{2x}+1). ~1e-7 abs err.
__device__ __forceinline__ float tanh_fast(float x) {
  float e = __expf(2.0f * x);
  return 1.0f - 2.0f / (e + 1.0f);
}

__device__ __forceinline__ void wave_sum64_2(float& a, float& b) {
#pragma unroll
  for (int m = 1; m < 64; m <<= 1) {
    a += __shfl_xor(a, m, 64);
    b += __shfl_xor(b, m, 64);
  }
}

// ---------------- Kernel 1: per-start branch net -> hc table ----------------
// 512 blocks x 8 rows. 256 threads; thread tid owns feature f=tid for ALL 8 rows
// (feature-split, not row-split): 4x fewer redundant bW1 reads per wave and 2 blocks/CU.
// GN(1 group): shfl butterfly (64-feat partial per wave) -> LDS[4 waves] -> broadcast combine.
#define R     8
#define HSTR  260
#define ESP   336              // espan floats (padded, 16B-aligned blocks)
#define OBS   320              // obsT[40][8]
#define GOFF  (ESP + OBS)      // gsum[4][8], gsq[4][8] = 64 floats
#define HOFF  (GOFF + 64)      // hbuf[8][HSTR]
#define SMEMF (HOFF + R * HSTR)

__global__ __launch_bounds__(256) void dc_precompute(
    const float* __restrict__ zc, const float* __restrict__ zt,
    const float* __restrict__ bW0, const float* __restrict__ bb0,
    const float* __restrict__ bs0, const float* __restrict__ bB0,
    const float* __restrict__ bW1, const float* __restrict__ bb1,
    const float* __restrict__ bs1, const float* __restrict__ bB1,
    const float* __restrict__ cW,  const float* __restrict__ cb,
    float* __restrict__ hc)
{
  __shared__ __align__(16) float smem[SMEMF];
  const int tid  = threadIdx.x;
  const int wave = tid >> 6;
  const int lane = tid & 63;
  const int s0   = blockIdx.x * R;

  float* espan = smem;          // [WINDOW + R - 1 = 334]
  float* obsT  = smem + ESP;    // [40][8] k-major
  float* gsum  = smem + GOFF;   // [4][8]
  float* gsq   = gsum + 32;     // [4][8]
  float* hbuf  = smem + HOFF;   // [8][HSTR]

  // Phase A: shared error span, edge-clamped (== jnp.pad 'edge')
  for (int t = tid; t < WINDOW + R - 1; t += 256) {
    int c = s0 - HALF + t;
    c = c < 0 ? 0 : (c > NP - 1 ? NP - 1 : c);
    espan[t] = zc[c] - zt[c];
  }
  __syncthreads();

  // Phase B: jax.image.resize(bilinear, antialias) of err & gradient -> obsT[40][8]
  {
    const float INV  = (float)WINDOW / (float)RL;   // 16.35
    const float RINV = (float)RL / (float)WINDOW;
    for (int task = tid; task < R * 2 * RL; task += 256) {
      int q = task % (2 * RL);
      int r = task / (2 * RL);
      int qq = (q < RL) ? q : q - RL;
      float xs = ((float)qq + 0.5f) * INV - 0.5f;
      int jlo = (int)ceilf(xs - INV);  if (jlo < 0) jlo = 0;
      int jhi = (int)floorf(xs + INV); if (jhi > WINDOW - 1) jhi = WINDOW - 1;
      const float* p = espan + r;
      float wsum = 0.0f, acc = 0.0f;
      for (int j = jlo; j <= jhi; ++j) {
        float w = 1.0f - fabsf(xs - (float)j) * RINV;
        float v;
        if (q < RL) {
          v = p[j];
        } else {  // jnp.gradient on the window
          v = (j == 0) ? (p[1] - p[0]) :
              (j == WINDOW - 1) ? (p[WINDOW - 1] - p[WINDOW - 2]) :
              0.5f * (p[j + 1] - p[j - 1]);
        }
        wsum += w;
        acc  += w * v;
      }
      obsT[q * R + r] = acc / wsum;
    }
  }
  __syncthreads();

  const int f = tid;  // feature owned by this thread (0..255)

  // Phase C: layer0 (40 -> 256): acc0[r] for 8 rows
  float acc0[R];
  {
    float b = bb0[f];
#pragma unroll
    for (int r = 0; r < R; ++r) acc0[r] = b;
    const float4* oT4 = (const float4*)obsT;
    for (int k = 0; k < 2 * RL; ++k) {
      float4 o1 = oT4[k * 2];       // rows 0..3 (LDS broadcast)
      float4 o2 = oT4[k * 2 + 1];   // rows 4..7
      float w = bW0[k * 256 + f];   // coalesced across 256 threads
      acc0[0] = fmaf(o1.x, w, acc0[0]); acc0[1] = fmaf(o1.y, w, acc0[1]);
      acc0[2] = fmaf(o1.z, w, acc0[2]); acc0[3] = fmaf(o1.w, w, acc0[3]);
      acc0[4] = fmaf(o2.x, w, acc0[4]); acc0[5] = fmaf(o2.y, w, acc0[5]);
      acc0[6] = fmaf(o2.z, w, acc0[6]); acc0[7] = fmaf(o2.w, w, acc0[7]);
    }
  }

  // Phase D: GroupNorm(1)+tanh. Wave partial (64 feats) via shfl, combine via LDS.
  {
#pragma unroll
    for (int r = 0; r < R; ++r) {
      float s = acc0[r], q = acc0[r] * acc0[r];
      wave_sum64_2(s, q);
      if (lane == 0) { gsum[wave * R + r] = s; gsq[wave * R + r] = q; }
    }
    __syncthreads();
    float scl = bs0[f], bia = bB0[f];
#pragma unroll
    for (int r = 0; r < R; ++r) {
      float s = gsum[r] + gsum[R + r] + gsum[2 * R + r] + gsum[3 * R + r];
      float q = gsq[r]  + gsq[R + r]  + gsq[2 * R + r]  + gsq[3 * R + r];
      float mu  = s * (1.0f / 256.0f);
      float var = fmaxf(q * (1.0f / 256.0f) - mu * mu, 0.0f);
      float rv  = rsqrtf(var + GN_EPS);
      hbuf[r * HSTR + f] = tanh_fast((acc0[r] - mu) * rv * scl + bia);
    }
  }
  __syncthreads();

  // Phase E: layer1 (256 -> 256)
  float acc1[R];
  {
    float b = bb1[f];
#pragma unroll
    for (int r = 0; r < R; ++r) acc1[r] = b;
    for (int kk = 0; kk < 256; kk += 4) {
      float4 h4[R];
#pragma unroll
      for (int r = 0; r < R; ++r) h4[r] = *(const float4*)&hbuf[r * HSTR + kk];
#pragma unroll
      for (int i = 0; i < 4; ++i) {
        float w = bW1[(kk + i) * 256 + f];
        float hv[R] = {((const float*)&h4[0])[i], ((const float*)&h4[1])[i],
                       ((const float*)&h4[2])[i], ((const float*)&h4[3])[i],
                       ((const float*)&h4[4])[i], ((const float*)&h4[5])[i],
                       ((const float*)&h4[6])[i], ((const float*)&h4[7])[i]};
#pragma unroll
        for (int r = 0; r < R; ++r) acc1[r] = fmaf(hv[r], w, acc1[r]);
      }
    }
  }
  __syncthreads();   // all h0 reads done before overwrite below

  // Phase F: GN + tanh -> h1 (reuse hbuf)
  {
#pragma unroll
    for (int r = 0; r < R; ++r) {
      float s = acc1[r], q = acc1[r] * acc1[r];
      wave_sum64_2(s, q);
      if (lane == 0) { gsum[wave * R + r] = s; gsq[wave * R + r] = q; }
    }
    __syncthreads();
    float scl = bs1[f], bia = bB1[f];
#pragma unroll
    for (int r = 0; r < R; ++r) {
      float s = gsum[r] + gsum[R + r] + gsum[2 * R + r] + gsum[3 * R + r];
      float q = gsq[r]  + gsq[R + r]  + gsq[2 * R + r]  + gsq[3 * R + r];
      float mu  = s * (1.0f / 256.0f);
      float var = fmaxf(q * (1.0f / 256.0f) - mu * mu, 0.0f);
      float rv  = rsqrtf(var + GN_EPS);
      hbuf[r * HSTR + f] = tanh_fast((acc1[r] - mu) * rv * scl + bia);
    }
  }
  __syncthreads();

  // Phase G: hc[row][j] = cb[j] + h1 . cW_top[:,j]  (256 threads = 8 rows x 32 cols)
  {
    int r = tid >> 5, j = tid & 31;
    float acc = cb[j];
    for (int kk = 0; kk < 256; kk += 4) {
      float4 hv = *(const float4*)&hbuf[r * HSTR + kk];
      acc = fmaf(hv.x, cW[(kk    ) * 32 + j], acc);
      acc = fmaf(hv.y, cW[(kk + 1) * 32 + j], acc);
      acc = fmaf(hv.z, cW[(kk + 2) * 32 + j], acc);
      acc = fmaf(hv.w, cW[(kk + 3) * 32 + j], acc);
    }
    hc[(s0 + r) * 32 + j] = acc;
  }
}

// ---------------- Kernel 2: per-agent trunk + combine + heads ----------------
// All weights staged once per block into LDS (~9.6 KB); compute reads are float4
// same-address broadcasts (conflict-free ds_read_b128, overlaps the VALU pipe).
#define W_T0   0        // tW0 [8][32]
#define W_T1   256      // tW1 [32][32]
#define W_CB   1280     // cW bottom rows [32][32]
#define W_B0   2304     // tb0[32]
#define W_B1   2336     // tb1[32]
#define W_UW   2368     // uW[32]
#define W_VW   2400     // vW[32]
#define W_SC   2432     // ub, vb
#define W_TOT  2448

__global__ __launch_bounds__(256) void dc_agents(
    const float* __restrict__ xi_curr, const float* __restrict__ hc,
    const float* __restrict__ tW0, const float* __restrict__ tb0,
    const float* __restrict__ tW1, const float* __restrict__ tb1,
    const float* __restrict__ cW,
    const float* __restrict__ uW, const float* __restrict__ ub,
    const float* __restrict__ vW, const float* __restrict__ vb,
    float* __restrict__ out)
{
  __shared__ __align__(16) float sW[W_TOT];
  const int tid = threadIdx.x;

  for (int i = tid; i < 256;  i += 256) sW[W_T0 + i] = tW0[i];
  for (int i = tid; i < 1024; i += 256) sW[W_T1 + i] = tW1[i];
  for (int i = tid; i < 1024; i += 256) sW[W_CB + i] = cW[256 * 32 + i];
  if (tid < 32) {
    sW[W_B0 + tid] = tb0[tid];
    sW[W_B1 + tid] = tb1[tid];
    sW[W_UW + tid] = uW[tid];
    sW[W_VW + tid] = vW[tid];
  }
  if (tid == 0) { sW[W_SC] = ub[0]; sW[W_SC + 1] = vb[0]; }
  __syncthreads();

  const int a = blockIdx.x * 256 + tid;
  float xi = xi_curr[a];
  int s = (int)(xi * 4095.0f);   // (xi*(N-1)).astype(int32)

  // Fourier features via angle doubling: sin/cos(pi*xi*{1,2,4,8})
  float ang = xi * 3.14159265358979323846f;
  float s1 = __sinf(ang), c1 = __cosf(ang);
  float s2 = 2.0f * s1 * c1, c2 = 1.0f - 2.0f * s1 * s1;
  float s4 = 2.0f * s2 * c2, c4 = 1.0f - 2.0f * s2 * s2;
  float s8 = 2.0f * s4 * c4, c8 = 1.0f - 2.0f * s4 * s4;
  float enc[8] = {s1, s2, s4, s8, c1, c2, c4, c8};

  float t0[32];
#pragma unroll
  for (int q = 0; q < 8; ++q) {
    float4 b = *(const float4*)&sW[W_B0 + 4 * q];
    t0[4*q] = b.x; t0[4*q+1] = b.y; t0[4*q+2] = b.z; t0[4*q+3] = b.w;
  }
#pragma unroll
  for (int k = 0; k < 8; ++k) {
    float e = enc[k];
#pragma unroll
    for (int q = 0; q < 8; ++q) {
      float4 w = *(const float4*)&sW[W_T0 + k * 32 + 4 * q];
      t0[4*q]   = fmaf(e, w.x, t0[4*q]);
      t0[4*q+1] = fmaf(e, w.y, t0[4*q+1]);
      t0[4*q+2] = fmaf(e, w.z, t0[4*q+2]);
      t0[4*q+3] = fmaf(e, w.w, t0[4*q+3]);
    }
  }
#pragma unroll
  for (int i = 0; i < 32; ++i) t0[i] = tanh_fast(t0[i]);

  float t1[32];
#pragma unroll
  for (int q = 0; q < 8; ++q) {
    float4 b = *(const float4*)&sW[W_B1 + 4 * q];
    t1[4*q] = b.x; t1[4*q+1] = b.y; t1[4*q+2] = b.z; t1[4*q+3] = b.w;
  }
#pragma unroll
  for (int k = 0; k < 32; ++k) {
    float e = t0[k];
#pragma unroll
    for (int q = 0; q < 8; ++q) {
      float4 w = *(const float4*)&sW[W_T1 + k * 32 + 4 * q];
      t1[4*q]   = fmaf(e, w.x, t1[4*q]);
      t1[4*q+1] = fmaf(e, w.y, t1[4*q+1]);
      t1[4*q+2] = fmaf(e, w.z, t1[4*q+2]);
      t1[4*q+3] = fmaf(e, w.w, t1[4*q+3]);
    }
  }
#pragma unroll
  for (int i = 0; i < 32; ++i) t1[i] = tanh_fast(t1[i]);

  // combined: hc[s] (includes h@cW_top + cb) + t1 @ cW_bot
  float xv[32];
  const float4* hp = (const float4*)(hc + s * 32);
#pragma unroll
  for (int q = 0; q < 8; ++q) {
    float4 h4 = hp[q];
    xv[4*q] = h4.x; xv[4*q+1] = h4.y; xv[4*q+2] = h4.z; xv[4*q+3] = h4.w;
  }
#pragma unroll
  for (int k = 0; k < 32; ++k) {
    float e = t1[k];
#pragma unroll
    for (int q = 0; q < 8; ++q) {
      float4 w = *(const float4*)&sW[W_CB + k * 32 + 4 * q];
      xv[4*q]   = fmaf(e, w.x, xv[4*q]);
      xv[4*q+1] = fmaf(e, w.y, xv[4*q+1]);
      xv[4*q+2] = fmaf(e, w.z, xv[4*q+2]);
      xv[4*q+3] = fmaf(e, w.w, xv[4*q+3]);
    }
  }

  float u = sW[W_SC], v = sW[W_SC + 1];
#pragma unroll
  for (int q = 0; q < 8; ++q) {
    float4 wu = *(const float4*)&sW[W_UW + 4 * q];
    float4 wv = *(const float4*)&sW[W_VW + 4 * q];
    float x0 = tanh_fast(xv[4*q]);
    float x1 = tanh_fast(xv[4*q+1]);
    float x2 = tanh_fast(xv[4*q+2]);
    float x3 = tanh_fast(xv[4*q+3]);
    u = fmaf(x0, wu.x, u); u = fmaf(x1, wu.y, u);
    u = fmaf(x2, wu.z, u); u = fmaf(x3, wu.w, u);
    v = fmaf(x0, wv.x, v); v = fmaf(x1, wv.y, v);
    v = fmaf(x2, wv.z, v); v = fmaf(x3, wv.w, v);
  }
  out[a]      = 40.0f * tanh_fast(u);
  out[NA + a] = tanh_fast(v);
}

extern "C" void kernel_launch(void* const* d_in, const int* in_sizes, int n_in,
                              void* d_out, int out_size, void* d_ws, size_t ws_size,
                              hipStream_t stream) {
  const float* zc  = (const float*)d_in[0];
  const float* zt  = (const float*)d_in[1];
  const float* xi  = (const float*)d_in[2];
  const float* bW0 = (const float*)d_in[3];
  const float* bb0 = (const float*)d_in[4];
  const float* bs0 = (const float*)d_in[5];
  const float* bB0 = (const float*)d_in[6];
  const float* bW1 = (const float*)d_in[7];
  const float* bb1 = (const float*)d_in[8];
  const float* bs1 = (const float*)d_in[9];
  const float* bB1 = (const float*)d_in[10];
  const float* tW0 = (const float*)d_in[11];
  const float* tb0 = (const float*)d_in[12];
  const float* tW1 = (const float*)d_in[13];
  const float* tb1 = (const float*)d_in[14];
  const float* cW  = (const float*)d_in[15];
  const float* cb  = (const float*)d_in[16];
  const float* uW  = (const float*)d_in[17];
  const float* ub  = (const float*)d_in[18];
  const float* vW  = (const float*)d_in[19];
  const float* vb  = (const float*)d_in[20];

  float* hc  = (float*)d_ws;    // 4096 x 32 fp32 = 512 KB
  float* out = (float*)d_out;   // [u(262144), v(262144)]

  dc_precompute<<<NP / R, 256, 0, stream>>>(zc, zt, bW0, bb0, bs0, bB0,
                                            bW1, bb1, bs1, bB1, cW, cb, hc);
  dc_agents<<<NA / 256, 256, 0, stream>>>(xi, hc, tW0, tb0, tW1, tb1, cW,
                                          uW, ub, vW, vb, out);
}

// Round 3
// 127.691 us; speedup vs baseline: 1.4804x; 1.4804x over previous
//
#include <hip/hip_runtime.h>

#define NP      4096
#define WINDOW  327
#define HALF    163
#define RL      20
#define NA      262144
#define GN_EPS  1e-6f
#define R       8          // rows (bins) per block
#define NBLK    (NP / R)   // 512 blocks

// fast tanh: 1 - 2/(e^{2x}+1), ~1e-7 abs err
__device__ __forceinline__ float tanh_fast(float x) {
  float e = __expf(2.0f * x);
  return 1.0f - 2.0f / (e + 1.0f);
}

// butterfly sum over 32-lane halves (masks <32 never cross the half boundary)
__device__ __forceinline__ void halfwave_sum2(float& a, float& b) {
#pragma unroll
  for (int m = 1; m < 32; m <<= 1) {
    a += __shfl_xor(a, m, 64);
    b += __shfl_xor(b, m, 64);
  }
}

// LDS layout (floats)
#define L_ESP   0               // espan[336]  (need 334)
#define L_OBS   336             // obsT[40][8]
#define L_HBUF  656             // hbuf[8][260]
#define L_PART  2736            // part[4][8][256] = 8192
#define L_HCL   10928           // hcL[8][36]
#define L_TOT   11216           // 44.9 KB

__global__ __launch_bounds__(256, 2) void dc_table(
    const float* __restrict__ zc,  const float* __restrict__ zt,
    const float* __restrict__ bW0, const float* __restrict__ bb0,
    const float* __restrict__ bs0, const float* __restrict__ bB0,
    const float* __restrict__ bW1, const float* __restrict__ bb1,
    const float* __restrict__ bs1, const float* __restrict__ bB1,
    const float* __restrict__ tW0, const float* __restrict__ tb0,
    const float* __restrict__ tW1, const float* __restrict__ tb1,
    const float* __restrict__ cW,  const float* __restrict__ cb,
    const float* __restrict__ uW,  const float* __restrict__ ub,
    const float* __restrict__ vW,  const float* __restrict__ vb,
    float* __restrict__ tbl)
{
  __shared__ __align__(16) float sm[L_TOT];
  float* espan = sm + L_ESP;
  float* obsT  = sm + L_OBS;    // [k][r], stride 8
  float* hbuf  = sm + L_HBUF;   // [r][f], stride 260
  float* part  = sm + L_PART;   // [w][r][f]
  float* hcL   = sm + L_HCL;    // [r][c], stride 36

  const int tid = threadIdx.x;
  const int w   = tid >> 6;
  const int l   = tid & 63;
  const int s0  = blockIdx.x * R;

  // ---- Phase A: shared error span (edge-clamped) ----
  for (int t = tid; t < WINDOW + R - 1; t += 256) {
    int c = s0 - HALF + t;
    c = c < 0 ? 0 : (c > NP - 1 ? NP - 1 : c);
    espan[t] = zc[c] - zt[c];
  }
  __syncthreads();

  // ---- Phase B: bilinear-antialias resize of err & gradient -> obsT[40][8] ----
  {
    const float INV  = (float)WINDOW / (float)RL;   // 16.35
    const float RINV = (float)RL / (float)WINDOW;
    for (int task = tid; task < R * 2 * RL; task += 256) {
      int q = task % (2 * RL);
      int r = task / (2 * RL);
      int qq = (q < RL) ? q : q - RL;
      float xs = ((float)qq + 0.5f) * INV - 0.5f;
      int jlo = (int)ceilf(xs - INV);  if (jlo < 0) jlo = 0;
      int jhi = (int)floorf(xs + INV); if (jhi > WINDOW - 1) jhi = WINDOW - 1;
      const float* p = espan + r;
      float wsum = 0.0f, acc = 0.0f;
      for (int j = jlo; j <= jhi; ++j) {
        float wq = 1.0f - fabsf(xs - (float)j) * RINV;
        float v;
        if (q < RL) {
          v = p[j];
        } else {
          v = (j == 0) ? (p[1] - p[0]) :
              (j == WINDOW - 1) ? (p[WINDOW - 1] - p[WINDOW - 2]) :
              0.5f * (p[j + 1] - p[j - 1]);
        }
        wsum += wq;
        acc  += wq * v;
      }
      obsT[q * 8 + r] = acc / wsum;
    }
  }
  __syncthreads();

  float acc[R][4];

  // ---- Layer 0 (40 -> 256), k-split: wave w owns k in [10w, 10w+10) ----
#pragma unroll
  for (int r = 0; r < R; ++r) { acc[r][0]=0.f; acc[r][1]=0.f; acc[r][2]=0.f; acc[r][3]=0.f; }
#pragma unroll 2
  for (int kk = 0; kk < 10; ++kk) {
    int k = w * 10 + kk;
    float4 wt = *(const float4*)&bW0[k * 256 + 4 * l];
    float4 o0 = *(const float4*)&obsT[k * 8];
    float4 o1 = *(const float4*)&obsT[k * 8 + 4];
    const float wv[4] = {wt.x, wt.y, wt.z, wt.w};
    const float ov[8] = {o0.x, o0.y, o0.z, o0.w, o1.x, o1.y, o1.z, o1.w};
#pragma unroll
    for (int r = 0; r < R; ++r)
#pragma unroll
      for (int j = 0; j < 4; ++j) acc[r][j] = fmaf(ov[r], wv[j], acc[r][j]);
  }

  // ---- combine + GN0 + tanh -> hbuf ----
  {
#pragma unroll
    for (int r = 0; r < R; ++r)
      *(float4*)&part[w * 2048 + r * 256 + 4 * l] = make_float4(acc[r][0], acc[r][1], acc[r][2], acc[r][3]);
    __syncthreads();
    int rr = tid >> 5, g = tid & 31;
    float val[8];
    {
      float4 b0 = *(const float4*)&bb0[8 * g];
      float4 b1 = *(const float4*)&bb0[8 * g + 4];
      val[0]=b0.x; val[1]=b0.y; val[2]=b0.z; val[3]=b0.w;
      val[4]=b1.x; val[5]=b1.y; val[6]=b1.z; val[7]=b1.w;
    }
#pragma unroll
    for (int w2 = 0; w2 < 4; ++w2) {
      float4 p0 = *(const float4*)&part[w2 * 2048 + rr * 256 + 8 * g];
      float4 p1 = *(const float4*)&part[w2 * 2048 + rr * 256 + 8 * g + 4];
      val[0]+=p0.x; val[1]+=p0.y; val[2]+=p0.z; val[3]+=p0.w;
      val[4]+=p1.x; val[5]+=p1.y; val[6]+=p1.z; val[7]+=p1.w;
    }
    float s = 0.f, q = 0.f;
#pragma unroll
    for (int i = 0; i < 8; ++i) { s += val[i]; q += val[i] * val[i]; }
    halfwave_sum2(s, q);
    float mu  = s * (1.0f / 256.0f);
    float var = fmaxf(q * (1.0f / 256.0f) - mu * mu, 0.0f);
    float rv  = rsqrtf(var + GN_EPS);
    float4 sc0 = *(const float4*)&bs0[8 * g];
    float4 sc1 = *(const float4*)&bs0[8 * g + 4];
    float4 sh0 = *(const float4*)&bB0[8 * g];
    float4 sh1 = *(const float4*)&bB0[8 * g + 4];
    const float sc[8] = {sc0.x,sc0.y,sc0.z,sc0.w,sc1.x,sc1.y,sc1.z,sc1.w};
    const float sh[8] = {sh0.x,sh0.y,sh0.z,sh0.w,sh1.x,sh1.y,sh1.z,sh1.w};
    float h[8];
#pragma unroll
    for (int i = 0; i < 8; ++i) h[i] = tanh_fast((val[i] - mu) * rv * sc[i] + sh[i]);
    *(float4*)&hbuf[rr * 260 + 8 * g]     = make_float4(h[0], h[1], h[2], h[3]);
    *(float4*)&hbuf[rr * 260 + 8 * g + 4] = make_float4(h[4], h[5], h[6], h[7]);
  }
  __syncthreads();

  // ---- Layer 1 (256 -> 256), k-split: wave w owns k in [64w, 64w+64) ----
#pragma unroll
  for (int r = 0; r < R; ++r) { acc[r][0]=0.f; acc[r][1]=0.f; acc[r][2]=0.f; acc[r][3]=0.f; }
#pragma unroll 2
  for (int kk = 0; kk < 64; kk += 4) {
    int k0 = w * 64 + kk;
    float4 wt0 = *(const float4*)&bW1[(k0    ) * 256 + 4 * l];
    float4 wt1 = *(const float4*)&bW1[(k0 + 1) * 256 + 4 * l];
    float4 wt2 = *(const float4*)&bW1[(k0 + 2) * 256 + 4 * l];
    float4 wt3 = *(const float4*)&bW1[(k0 + 3) * 256 + 4 * l];
    float4 hr[R];
#pragma unroll
    for (int r = 0; r < R; ++r) hr[r] = *(const float4*)&hbuf[r * 260 + k0];
#pragma unroll
    for (int r = 0; r < R; ++r) {
      const float* hp = (const float*)&hr[r];
      acc[r][0] = fmaf(hp[0], wt0.x, acc[r][0]); acc[r][1] = fmaf(hp[0], wt0.y, acc[r][1]);
      acc[r][2] = fmaf(hp[0], wt0.z, acc[r][2]); acc[r][3] = fmaf(hp[0], wt0.w, acc[r][3]);
      acc[r][0] = fmaf(hp[1], wt1.x, acc[r][0]); acc[r][1] = fmaf(hp[1], wt1.y, acc[r][1]);
      acc[r][2] = fmaf(hp[1], wt1.z, acc[r][2]); acc[r][3] = fmaf(hp[1], wt1.w, acc[r][3]);
      acc[r][0] = fmaf(hp[2], wt2.x, acc[r][0]); acc[r][1] = fmaf(hp[2], wt2.y, acc[r][1]);
      acc[r][2] = fmaf(hp[2], wt2.z, acc[r][2]); acc[r][3] = fmaf(hp[2], wt2.w, acc[r][3]);
      acc[r][0] = fmaf(hp[3], wt3.x, acc[r][0]); acc[r][1] = fmaf(hp[3], wt3.y, acc[r][1]);
      acc[r][2] = fmaf(hp[3], wt3.z, acc[r][2]); acc[r][3] = fmaf(hp[3], wt3.w, acc[r][3]);
    }
  }

  // ---- combine + GN1 + tanh -> hbuf (overwrites h0; all reads completed pre-sync) ----
  {
#pragma unroll
    for (int r = 0; r < R; ++r)
      *(float4*)&part[w * 2048 + r * 256 + 4 * l] = make_float4(acc[r][0], acc[r][1], acc[r][2], acc[r][3]);
    __syncthreads();
    int rr = tid >> 5, g = tid & 31;
    float val[8];
    {
      float4 b0 = *(const float4*)&bb1[8 * g];
      float4 b1 = *(const float4*)&bb1[8 * g + 4];
      val[0]=b0.x; val[1]=b0.y; val[2]=b0.z; val[3]=b0.w;
      val[4]=b1.x; val[5]=b1.y; val[6]=b1.z; val[7]=b1.w;
    }
#pragma unroll
    for (int w2 = 0; w2 < 4; ++w2) {
      float4 p0 = *(const float4*)&part[w2 * 2048 + rr * 256 + 8 * g];
      float4 p1 = *(const float4*)&part[w2 * 2048 + rr * 256 + 8 * g + 4];
      val[0]+=p0.x; val[1]+=p0.y; val[2]+=p0.z; val[3]+=p0.w;
      val[4]+=p1.x; val[5]+=p1.y; val[6]+=p1.z; val[7]+=p1.w;
    }
    float s = 0.f, q = 0.f;
#pragma unroll
    for (int i = 0; i < 8; ++i) { s += val[i]; q += val[i] * val[i]; }
    halfwave_sum2(s, q);
    float mu  = s * (1.0f / 256.0f);
    float var = fmaxf(q * (1.0f / 256.0f) - mu * mu, 0.0f);
    float rv  = rsqrtf(var + GN_EPS);
    float4 sc0 = *(const float4*)&bs1[8 * g];
    float4 sc1 = *(const float4*)&bs1[8 * g + 4];
    float4 sh0 = *(const float4*)&bB1[8 * g];
    float4 sh1 = *(const float4*)&bB1[8 * g + 4];
    const float sc[8] = {sc0.x,sc0.y,sc0.z,sc0.w,sc1.x,sc1.y,sc1.z,sc1.w};
    const float sh[8] = {sh0.x,sh0.y,sh0.z,sh0.w,sh1.x,sh1.y,sh1.z,sh1.w};
    float h[8];
#pragma unroll
    for (int i = 0; i < 8; ++i) h[i] = tanh_fast((val[i] - mu) * rv * sc[i] + sh[i]);
    *(float4*)&hbuf[rr * 260 + 8 * g]     = make_float4(h[0], h[1], h[2], h[3]);
    *(float4*)&hbuf[rr * 260 + 8 * g + 4] = make_float4(h[4], h[5], h[6], h[7]);
  }
  __syncthreads();

  // ---- Phase G: hcL[r][c] = cb[c] + h1[r,:] . cW[:,c]  (256 threads = 8r x 32c) ----
  {
    int r = tid >> 5, c = tid & 31;
    float ga = cb[c];
#pragma unroll 4
    for (int k = 0; k < 256; k += 4) {
      float4 hv = *(const float4*)&hbuf[r * 260 + k];
      ga = fmaf(hv.x, cW[(k    ) * 32 + c], ga);
      ga = fmaf(hv.y, cW[(k + 1) * 32 + c], ga);
      ga = fmaf(hv.z, cW[(k + 2) * 32 + c], ga);
      ga = fmaf(hv.w, cW[(k + 3) * 32 + c], ga);
    }
    hcL[r * 36 + c] = ga;
  }
  __syncthreads();

  // ---- Tail: 16 endpoint evals (8 bins x {left,right}), 8 threads each ----
  if (tid < 128) {
    int v = tid >> 3, sub = tid & 7;
    int r = v >> 1, e = v & 1;
    int jg = s0 + r + e;                      // grid point; hc stays hcL[r]
    float xe = (float)jg * (1.0f / 4095.0f);
    float enc[8];
#pragma unroll
    for (int k = 0; k < 4; ++k) {
      float fr = (float)(1 << k);
      float a = (xe * fr) * 3.14159265358979f;
      enc[k]     = sinf(a);
      enc[k + 4] = cosf(a);
    }
    int base = (tid & 63) & ~7;               // octet base lane within wave

    float t0v[4];
#pragma unroll
    for (int i = 0; i < 4; ++i) {
      int f = 4 * sub + i;
      float a = tb0[f];
#pragma unroll
      for (int k = 0; k < 8; ++k) a = fmaf(enc[k], tW0[k * 32 + f], a);
      t0v[i] = tanh_fast(a);
    }

    float t1v[4];
#pragma unroll
    for (int i = 0; i < 4; ++i) t1v[i] = tb1[4 * sub + i];
#pragma unroll
    for (int j8 = 0; j8 < 8; ++j8) {
#pragma unroll
      for (int i2 = 0; i2 < 4; ++i2) {
        float tv = __shfl(t0v[i2], base + j8, 64);
        int k = 4 * j8 + i2;
#pragma unroll
        for (int i = 0; i < 4; ++i) t1v[i] = fmaf(tv, tW1[k * 32 + 4 * sub + i], t1v[i]);
      }
    }
#pragma unroll
    for (int i = 0; i < 4; ++i) t1v[i] = tanh_fast(t1v[i]);

    float xvv[4];
#pragma unroll
    for (int i = 0; i < 4; ++i) xvv[i] = hcL[r * 36 + 4 * sub + i];
#pragma unroll
    for (int j8 = 0; j8 < 8; ++j8) {
#pragma unroll
      for (int i2 = 0; i2 < 4; ++i2) {
        float tv = __shfl(t1v[i2], base + j8, 64);
        int k = 4 * j8 + i2;
#pragma unroll
        for (int i = 0; i < 4; ++i) xvv[i] = fmaf(tv, cW[(256 + k) * 32 + 4 * sub + i], xvv[i]);
      }
    }
#pragma unroll
    for (int i = 0; i < 4; ++i) xvv[i] = tanh_fast(xvv[i]);

    float up = 0.f, vp = 0.f;
#pragma unroll
    for (int i = 0; i < 4; ++i) {
      up = fmaf(xvv[i], uW[4 * sub + i], up);
      vp = fmaf(xvv[i], vW[4 * sub + i], vp);
    }
#pragma unroll
    for (int m = 1; m < 8; m <<= 1) {
      up += __shfl_xor(up, m, 64);
      vp += __shfl_xor(vp, m, 64);
    }
    if (sub == 0) {
      int s = s0 + r;
      tbl[4 * s + e]     = 40.0f * tanh_fast(up + ub[0]);
      tbl[4 * s + 2 + e] = tanh_fast(vp + vb[0]);
    }
  }
}

// ---------------- Kernel 2: agents = bin + lerp ----------------
__global__ __launch_bounds__(256) void dc_agents(
    const float* __restrict__ xi_curr, const float4* __restrict__ tbl,
    float* __restrict__ out)
{
  int a = blockIdx.x * 256 + threadIdx.x;
  float xi = xi_curr[a];
  float p = xi * 4095.0f;           // same fp32 product the reference truncates
  int s = (int)p;
  s = s > 4095 ? 4095 : s;
  float t = p - (float)s;           // exact (Sterbenz)
  float4 tb = tbl[s];               // {u_l, u_r, v_l, v_r}
  out[a]      = fmaf(t, tb.y - tb.x, tb.x);
  out[NA + a] = fmaf(t, tb.w - tb.z, tb.z);
}

extern "C" void kernel_launch(void* const* d_in, const int* in_sizes, int n_in,
                              void* d_out, int out_size, void* d_ws, size_t ws_size,
                              hipStream_t stream) {
  const float* zc  = (const float*)d_in[0];
  const float* zt  = (const float*)d_in[1];
  const float* xi  = (const float*)d_in[2];
  const float* bW0 = (const float*)d_in[3];
  const float* bb0 = (const float*)d_in[4];
  const float* bs0 = (const float*)d_in[5];
  const float* bB0 = (const float*)d_in[6];
  const float* bW1 = (const float*)d_in[7];
  const float* bb1 = (const float*)d_in[8];
  const float* bs1 = (const float*)d_in[9];
  const float* bB1 = (const float*)d_in[10];
  const float* tW0 = (const float*)d_in[11];
  const float* tb0 = (const float*)d_in[12];
  const float* tW1 = (const float*)d_in[13];
  const float* tb1 = (const float*)d_in[14];
  const float* cW  = (const float*)d_in[15];
  const float* cb  = (const float*)d_in[16];
  const float* uW  = (const float*)d_in[17];
  const float* ub  = (const float*)d_in[18];
  const float* vW  = (const float*)d_in[19];
  const float* vb  = (const float*)d_in[20];

  float* tbl = (float*)d_ws;        // 4096 x float4 = 64 KB
  float* out = (float*)d_out;

  dc_table<<<NBLK, 256, 0, stream>>>(zc, zt, bW0, bb0, bs0, bB0,
                                     bW1, bb1, bs1, bB1,
                                     tW0, tb0, tW1, tb1, cW, cb,
                                     uW, ub, vW, vb, tbl);
  dc_agents<<<NA / 256, 256, 0, stream>>>(xi, (const float4*)tbl, out);
}